// Round 9
// baseline (165.959 us; speedup 1.0000x reference)
//
#include <hip/hip_runtime.h>

// Pose_Loss: B=65536 rows, D=154 cols, 4 fp32 arrays + 2 int mask arrays.
// out[0] = (dot(use_l, rowsum(recon_l)) + dot(use_r, rowsum(recon_r))) / 154
// out[1] =  dot(use_l, rowsum(KLD_l))   + dot(use_r, rowsum(KLD_r))
// out[2] =  sum(use_l) + sum(use_r)   (integer count, stored as float)
//
// R9 = R8 with ITERS=2: 4928 blocks, 8 independent nt float4 loads issued
// up-front per thread. Rationale: R8's main kernel delivers 4.3 TB/s vs
// ~6.5 TB/s proven in-window (harness fills); with 1 chunk/thread each
// wave pays a ~450-cyc reduction tail + retire per 4 KB moved (~30% duty
// loss). ITERS=2 halves tails/blocks per byte and doubles per-wave
// in-flight bytes. (R4 tested this under the write-allocate ceiling where
// it couldn't show; nt loads changed the binding constraint.)
//  - nt loads (confirmed R6): no L3 allocation -> no eviction of the
//    harness restore's dirty lines -> no hidden in-window writeback.
//  - D = 154 = 2*77 => a float2 half never straddles a row; float4 chunk i
//    covers halves 2i, 2i+1 with rows (2i)/77, (2i+1)/77 (branch-free).
//  - Two-stage reduction via d_ws + tiny second launch (R7 proved the
//    threadfence single-kernel alternative costs 100x).

#define BB 65536
#define DD 154
#define N4 (BB * DD / 4)          // 2,523,136
#define THREADS 256
#define ITERS 2
#define BLOCKS (N4 / (THREADS * ITERS))   // 4928
#define TSTRIDE (BLOCKS * THREADS)        // 1,261,568
#define CNT_BLOCKS (BB / THREADS)         // 256

typedef float nt_float4 __attribute__((ext_vector_type(4)));

__global__ void zero_out_kernel(float* __restrict__ out) {
    if (threadIdx.x < 3) out[threadIdx.x] = 0.0f;
}

__device__ __forceinline__ float2 wpair(int l, int f) {
    const bool valid = (f != -1);
    float2 w;
    w.x = (valid && ((l == 0) || (l == 2))) ? 1.0f : 0.0f;
    w.y = (valid && ((l == 1) || (l == 2))) ? 1.0f : 0.0f;
    return w;
}

// ws layout: ws[0..BLOCKS) = recon partials, [B..2B) = kld, [2B..3B) = cnt
__global__ __launch_bounds__(THREADS) void pose_partial_kernel(
    const float* __restrict__ recon_l, const float* __restrict__ recon_r,
    const float* __restrict__ kld_l,   const float* __restrict__ kld_r,
    const int* __restrict__ lr,        const int* __restrict__ fp,
    float* __restrict__ ws,            float* __restrict__ out)
{
    const nt_float4* __restrict__ rl4 = (const nt_float4*)recon_l;
    const nt_float4* __restrict__ rr4 = (const nt_float4*)recon_r;
    const nt_float4* __restrict__ kl4 = (const nt_float4*)kld_l;
    const nt_float4* __restrict__ kr4 = (const nt_float4*)kld_r;

    const int i0 = blockIdx.x * THREADS + threadIdx.x;  // chunk for iter 0
    const int i1 = i0 + TSTRIDE;                        // chunk for iter 1

    // all 8 streaming loads issued up front (independent, no L3 allocate)
    const nt_float4 a0 = __builtin_nontemporal_load(&rl4[i0]);
    const nt_float4 b0 = __builtin_nontemporal_load(&rr4[i0]);
    const nt_float4 c0 = __builtin_nontemporal_load(&kl4[i0]);
    const nt_float4 d0 = __builtin_nontemporal_load(&kr4[i0]);
    const nt_float4 a1 = __builtin_nontemporal_load(&rl4[i1]);
    const nt_float4 b1 = __builtin_nontemporal_load(&rr4[i1]);
    const nt_float4 c1 = __builtin_nontemporal_load(&kl4[i1]);
    const nt_float4 d1 = __builtin_nontemporal_load(&kr4[i1]);

    // weight lookups stay cached (tiny, heavily reused across lanes)
    const int h0 = 2 * i0;
    const int r00 = h0 / 77, r01 = (h0 + 1) / 77;
    const int h1 = 2 * i1;
    const int r10 = h1 / 77, r11 = (h1 + 1) / 77;
    const float2 w00 = wpair(lr[r00], fp[r00]);
    const float2 w01 = wpair(lr[r01], fp[r01]);
    const float2 w10 = wpair(lr[r10], fp[r10]);
    const float2 w11 = wpair(lr[r11], fp[r11]);

    float acc_recon =
          w00.x * (a0.x + a0.y) + w01.x * (a0.z + a0.w)
        + w00.y * (b0.x + b0.y) + w01.y * (b0.z + b0.w)
        + w10.x * (a1.x + a1.y) + w11.x * (a1.z + a1.w)
        + w10.y * (b1.x + b1.y) + w11.y * (b1.z + b1.w);
    float acc_kld =
          w00.x * (c0.x + c0.y) + w01.x * (c0.z + c0.w)
        + w00.y * (d0.x + d0.y) + w01.y * (d0.z + d0.w)
        + w10.x * (c1.x + c1.y) + w11.x * (c1.z + c1.w)
        + w10.y * (d1.x + d1.y) + w11.y * (d1.z + d1.w);

    // mask count via ballot popcount: blocks 0..255 own rows i0 < BB.
    float n_wave = 0.0f;
    if (blockIdx.x < CNT_BLOCKS) {
        const float2 w = wpair(lr[i0], fp[i0]);
        n_wave = (float)(__popcll(__ballot(w.x != 0.0f)) +
                         __popcll(__ballot(w.y != 0.0f)));
    }

#pragma unroll
    for (int off = 32; off > 0; off >>= 1) {
        acc_recon += __shfl_down(acc_recon, off, 64);
        acc_kld   += __shfl_down(acc_kld,   off, 64);
    }

    __shared__ float s_r[4], s_k[4], s_n[4];
    const int wave = threadIdx.x >> 6;
    const int lane = threadIdx.x & 63;
    if (lane == 0) {
        s_r[wave] = acc_recon;
        s_k[wave] = acc_kld;
        s_n[wave] = n_wave;
    }
    __syncthreads();

    if (threadIdx.x == 0) {
        const float r = s_r[0] + s_r[1] + s_r[2] + s_r[3];
        const float k = s_k[0] + s_k[1] + s_k[2] + s_k[3];
        const float n = s_n[0] + s_n[1] + s_n[2] + s_n[3];
        if (ws != nullptr) {
            ws[blockIdx.x]              = r;
            ws[BLOCKS + blockIdx.x]     = k;
            ws[2 * BLOCKS + blockIdx.x] = n;
        } else {
            atomicAdd(&out[0], r * (1.0f / 154.0f));
            atomicAdd(&out[1], k);
            atomicAdd(&out[2], n);
        }
    }
}

__global__ __launch_bounds__(1024) void final_reduce_kernel(
    const float* __restrict__ ws, float* __restrict__ out)
{
    float r = 0.0f, k = 0.0f, n = 0.0f;
    for (int i = threadIdx.x; i < BLOCKS; i += 1024) {
        r += ws[i];
        k += ws[BLOCKS + i];
        n += ws[2 * BLOCKS + i];
    }
#pragma unroll
    for (int off = 32; off > 0; off >>= 1) {
        r += __shfl_down(r, off, 64);
        k += __shfl_down(k, off, 64);
        n += __shfl_down(n, off, 64);
    }
    __shared__ float s_r[16], s_k[16], s_n[16];
    const int wave = threadIdx.x >> 6;
    const int lane = threadIdx.x & 63;
    if (lane == 0) { s_r[wave] = r; s_k[wave] = k; s_n[wave] = n; }
    __syncthreads();
    if (threadIdx.x == 0) {
        float rr = 0.0f, kk = 0.0f, nn = 0.0f;
#pragma unroll
        for (int w = 0; w < 16; ++w) { rr += s_r[w]; kk += s_k[w]; nn += s_n[w]; }
        out[0] = rr * (1.0f / 154.0f);
        out[1] = kk;
        out[2] = nn;
    }
}

extern "C" void kernel_launch(void* const* d_in, const int* in_sizes, int n_in,
                              void* d_out, int out_size, void* d_ws, size_t ws_size,
                              hipStream_t stream) {
    const float* recon_l = (const float*)d_in[0];
    const float* recon_r = (const float*)d_in[1];
    const float* kld_l   = (const float*)d_in[2];
    const float* kld_r   = (const float*)d_in[3];
    const int*   lr      = (const int*)d_in[4];
    const int*   fp      = (const int*)d_in[5];
    float* out = (float*)d_out;

    const bool use_ws = (d_ws != nullptr) &&
                        (ws_size >= (size_t)(3 * BLOCKS) * sizeof(float));
    float* ws = use_ws ? (float*)d_ws : nullptr;

    if (!use_ws) {
        zero_out_kernel<<<1, 64, 0, stream>>>(out);
    }
    pose_partial_kernel<<<BLOCKS, THREADS, 0, stream>>>(
        recon_l, recon_r, kld_l, kld_r, lr, fp, ws, out);
    if (use_ws) {
        final_reduce_kernel<<<1, 1024, 0, stream>>>(ws, out);
    }
}